// Round 6
// baseline (367.654 us; speedup 1.0000x reference)
//
#include <hip/hip_runtime.h>

typedef unsigned short u16;
typedef unsigned int u32;
typedef float f32x4 __attribute__((ext_vector_type(4)));
typedef short bf16x8 __attribute__((ext_vector_type(8)));

#define NB 8
#define FH 37
#define FW 50
#define FHW 1850
#define MTOT 14800
#define CIN 512
#define KTOT 4608
#define HP 39
#define WP 52
#define ANCH 16650
#define NG 20

// k_pre block ranges
#define ZB 356            // pad-ring zero
#define WTB 512           // w3 repack (LDS transpose, 1 block per n)
#define WHB 128           // head-weight repack
#define TRB 7424          // NHWC transpose
#define PRE_TOT (ZB + WTB + WHB + TRB)   // +1 extra block zeroes band counters

// k_conv block ranges
#define CONVB 960         // 116 mb x 8 nb (with XCD swizzle; 32 dead blocks)
#define IOB 528           // 66 x 8 iou blocks ride along

// ---------- helpers ----------
__device__ __forceinline__ u16 f2bf(float f) {
    u32 u = __float_as_uint(f);
    u += 0x7fffu + ((u >> 16) & 1u);   // round-to-nearest-even
    return (u16)(u >> 16);
}

__device__ __forceinline__ void gl2lds16(const u16* g, u16* l) {
    __builtin_amdgcn_global_load_lds((const __attribute__((address_space(1))) void*)(g),
                                     (__attribute__((address_space(3))) void*)(l),
                                     16, 0, 0);
}

__device__ __forceinline__ void anchor_box(int a, float& x1, float& y1, float& x2, float& y2) {
    int x = a / 333;
    int rem = a - x * 333;
    int y = rem / 9;
    int r2 = rem - y * 9;
    int si = r2 / 3;
    int bi = r2 - si * 3;
    float s = (float)(8 << si);
    float fx = (float)x, fy = (float)y;
    float ax1, ay1, ax2, ay2;
    if (bi == 0)      { float h = s * 0.5f;  ax1 = fx - h; ay1 = fy - h; ax2 = fx + h; ay2 = fy + h; }
    else if (bi == 1) { float q = s * 0.25f; ax1 = fx - s; ay1 = fy - q; ax2 = fx + s; ay2 = fy + q; }
    else              { float q = s * 0.25f; ax1 = fx - q; ay1 = fy - s; ax2 = fx + q; ay2 = fy + s; }
    x1 = ax1 * 16.f; y1 = ay1 * 16.f; x2 = ax2 * 16.f; y2 = ay2 * 16.f;
}

// ---------- fused prep ----------
__global__ __launch_bounds__(256) void k_pre(u16* __restrict__ apad,
                                             const float* __restrict__ w3, u16* __restrict__ wt,
                                             const float* __restrict__ wc, const float* __restrict__ wb,
                                             u16* __restrict__ whd,
                                             const float* __restrict__ feats,
                                             int* __restrict__ cnt) {
    __shared__ __attribute__((aligned(16))) char smraw[18432];
    int blk = blockIdx.x;
    int t = threadIdx.x;

    if (blk < ZB) {
        // zero only the 1-px pad ring (interior overwritten by transpose)
        uint4* apad4 = (uint4*)apad;
        int i = blk * 256 + t;               // < 91136
        int img = i / 11392;
        int r = i - img * 11392;
        int u4;
        if (r < 3328) u4 = r;                                   // row 0
        else if (r < 6656) u4 = 126464 + (r - 3328);            // row 38
        else {
            int rp = r - 6656;
            int h = 1 + (rp >> 7);
            int c2 = rp & 127;
            int col = (c2 & 64) ? 51 : 0;
            u4 = (h * 52 + col) * 64 + (c2 & 63);
        }
        apad4[img * 129792 + u4] = make_uint4(0u, 0u, 0u, 0u);
    } else if (blk < ZB + WTB) {
        // w3[n] (512,3,3) -> wt[n][tap*512+ci], coalesced via LDS transpose
        float* lt = (float*)smraw;           // 4608 floats
        int n = blk - ZB;
        const float* src = w3 + n * KTOT;
        for (int i = t; i < KTOT; i += 256) lt[i] = src[i];
        __syncthreads();
        u16* dst = wt + n * KTOT;
        for (int o = t; o < KTOT; o += 256) {
            int tap = o >> 9, ci = o & 511;
            dst[o] = f2bf(lt[ci * 9 + tap]);
        }
    } else if (blk < ZB + WTB + WHB) {
        int i = (blk - ZB - WTB) * 256 + t;
        int n = i >> 9;
        int ci = i & 511;
        float v = 0.f;
        if (n < 18) v = wc[n * 512 + ci];
        else if (n < 54) v = wb[(n - 18) * 512 + ci];
        whd[i] = f2bf(v);
    } else if (blk < PRE_TOT) {
        // feats (B,512,37,50) f32 -> apad (B,39,52,512) bf16 interior
        float* tile = (float*)smraw;         // 32x33 floats
        int q = blk - ZB - WTB - WHB;
        int xt = q % 58;
        int r2 = q / 58;
        int ct = r2 & 15;
        int img = r2 >> 4;
        int hw0 = xt * 32, c0 = ct * 32;
        int tx = t & 31, ty4 = t >> 5;
        #pragma unroll
        for (int rr = 0; rr < 4; rr++) {
            int ty = ty4 + rr * 8;
            int hw = hw0 + tx;
            if (hw < FHW) tile[ty * 33 + tx] = feats[(img * 512 + c0 + ty) * FHW + hw];
        }
        __syncthreads();
        #pragma unroll
        for (int rr = 0; rr < 4; rr++) {
            int ty = ty4 + rr * 8;
            int hw2 = hw0 + ty;
            if (hw2 < FHW) {
                int h = hw2 / FW, w = hw2 - h * FW;
                apad[(((img * HP) + h + 1) * WP + (w + 1)) * 512 + c0 + tx] = f2bf(tile[tx * 33 + ty]);
            }
        }
    } else {
        // zero band counters (ws is re-poisoned 0xAA before every launch)
        if (t < 116) cnt[t] = 0;
    }
}

// ---------- 3x3 conv implicit GEMM + ticketed fused post + IoU tail ----------
// Conv: BM=128 BN=64 BK=64 full-K. XCD decode: all 8 nb of one mb share L%8
// (one XCD) so the A-tile and the act band stay in that XCD's L2.
// After each block writes its bf16 act slice it bumps cnt[mb] with an
// acq_rel agent-scope RMW; the 8th (last) block runs the head GEMM +
// softmax + concat for the 128-row band.
__global__ __launch_bounds__(256) void k_conv(const u16* __restrict__ apad,
                                              const u16* __restrict__ wt,
                                              const float* __restrict__ b3,
                                              const float* __restrict__ bc,
                                              const float* __restrict__ bb,
                                              const u16* __restrict__ whd,
                                              u16* __restrict__ act,
                                              int* __restrict__ cnt,
                                              const float* __restrict__ gt,
                                              const float* __restrict__ im,
                                              float* __restrict__ iou_out,
                                              float* __restrict__ lab,
                                              float* __restrict__ out) {
    __shared__ __attribute__((aligned(16))) char sm[33280];   // 128*65 f32 post tile
    __shared__ int idxs;
    __shared__ int flagv;
    int L = blockIdx.x;
    int tid = threadIdx.x;

    if (L < CONVB) {
        u16* As = (u16*)sm;                 // 128x64 bf16, 16 KB
        u16* Bs = (u16*)(sm + 16384);       // 64x64 bf16, 8 KB
        int mb = (L & 7) + 8 * (L >> 6);
        int nb = (L >> 3) & 7;
        if (mb >= 116) return;
        int wave = tid >> 6, lane = tid & 63;
        int m0 = mb * 128;
        int n0 = nb * 64;
        int wr = wave >> 1, wn = wave & 1;
        int lm = lane & 15, lq = lane >> 4;
        int l7 = lm & 7;

        f32x4 acc[4][2] = {};

        int rloc = tid >> 3;
        int cg = (tid & 7) ^ (rloc & 7);
        int aBase[4], bBase[2];
        for (int i = 0; i < 4; i++) {
            int m = m0 + i * 32 + rloc; if (m > MTOT - 1) m = MTOT - 1;
            int b = m / FHW; int hw = m - b * FHW;
            int h = hw / FW; int w = hw - h * FW;
            aBase[i] = ((b * HP + h) * WP + w) * 512 + cg * 8;
        }
        for (int j = 0; j < 2; j++)
            bBase[j] = (n0 + j * 32 + rloc) * KTOT + cg * 8;

        u16* aL[4]; u16* bL[2];
        for (int i = 0; i < 4; i++) aL[i] = &As[(i * 32 + wave * 8) * 64];
        for (int j = 0; j < 2; j++) bL[j] = &Bs[(j * 32 + wave * 8) * 64];

        for (int kk = 0; kk < KTOT; kk += 64) {
            int tap = kk >> 9;
            int ci0 = kk & 511;
            int dy = tap / 3, dx = tap - dy * 3;
            int aOfs = (dy * WP + dx) * 512 + ci0;
            gl2lds16(apad + aBase[0] + aOfs, aL[0]);
            gl2lds16(apad + aBase[1] + aOfs, aL[1]);
            gl2lds16(apad + aBase[2] + aOfs, aL[2]);
            gl2lds16(apad + aBase[3] + aOfs, aL[3]);
            gl2lds16(wt + bBase[0] + kk, bL[0]);
            gl2lds16(wt + bBase[1] + kk, bL[1]);
            __syncthreads();
            bf16x8 a[2][4], b[2][2];
            #pragma unroll
            for (int ks = 0; ks < 2; ks++) {
                int slotb = ((ks * 4 + lq) ^ l7) * 8;
                #pragma unroll
                for (int i = 0; i < 4; i++)
                    a[ks][i] = *(const bf16x8*)&As[(wr * 64 + i * 16 + lm) * 64 + slotb];
                #pragma unroll
                for (int j = 0; j < 2; j++)
                    b[ks][j] = *(const bf16x8*)&Bs[(wn * 32 + j * 16 + lm) * 64 + slotb];
            }
            #pragma unroll
            for (int ks = 0; ks < 2; ks++)
                #pragma unroll
                for (int i = 0; i < 4; i++)
                    #pragma unroll
                    for (int j = 0; j < 2; j++)
                        acc[i][j] = __builtin_amdgcn_mfma_f32_16x16x32_bf16(a[ks][i], b[ks][j], acc[i][j], 0, 0, 0);
            __syncthreads();
        }

        // epilogue: bias + relu + bf16 act
        for (int j = 0; j < 2; j++) {
            int n = n0 + wn * 32 + j * 16 + lm;
            float bias = b3[n];
            for (int i = 0; i < 4; i++) {
                int mb2 = m0 + wr * 64 + i * 16 + lq * 4;
                for (int r = 0; r < 4; r++) {
                    int m = mb2 + r;
                    if (m < MTOT) {
                        float v = acc[i][j][r] + bias;
                        act[m * 512 + n] = f2bf(v > 0.f ? v : 0.f);
                    }
                }
            }
        }

        // ticket: last of the 8 nb-blocks for this band runs the head
        __syncthreads();
        __threadfence();
        if (tid == 0) {
            int old = __hip_atomic_fetch_add(&cnt[mb], 1, __ATOMIC_ACQ_REL,
                                             __HIP_MEMORY_SCOPE_AGENT);
            flagv = (old == 7);
        }
        __syncthreads();
        if (!flagv) return;
        __threadfence();

        // ---- fused post for rows m0..m0+127 ----
        // head GEMM: each wave handles 32 rows, full K=512
        float* Sl2 = (float*)sm;             // 128 x 65 floats = 33280 B
        f32x4 acc2[2][4] = {};
        int r0 = wave * 32;
        int arow[2];
        for (int i = 0; i < 2; i++) {
            int m = m0 + r0 + i * 16 + lm; if (m > MTOT - 1) m = MTOT - 1;
            arow[i] = m * 512;
        }
        for (int kk = 0; kk < 512; kk += 32) {
            bf16x8 a[2], b[4];
            #pragma unroll
            for (int i = 0; i < 2; i++)
                a[i] = *(const bf16x8*)&act[arow[i] + kk + lq * 8];
            #pragma unroll
            for (int j = 0; j < 4; j++)
                b[j] = *(const bf16x8*)&whd[(j * 16 + lm) * 512 + kk + lq * 8];
            #pragma unroll
            for (int i = 0; i < 2; i++)
                #pragma unroll
                for (int j = 0; j < 4; j++)
                    acc2[i][j] = __builtin_amdgcn_mfma_f32_16x16x32_bf16(a[i], b[j], acc2[i][j], 0, 0, 0);
        }
        #pragma unroll
        for (int i = 0; i < 2; i++)
            #pragma unroll
            for (int r = 0; r < 4; r++)
                #pragma unroll
                for (int j = 0; j < 4; j++)
                    Sl2[(r0 + i * 16 + lq * 4 + r) * 65 + j * 16 + lm] = acc2[i][j][r];
        __syncthreads();

        // softmax pairs + bbox bias, coalesced channel-major write
        for (int i = tid; i < 54 * 128; i += 256) {
            int cc = i >> 7, row = i & 127;
            int m = m0 + row;
            if (m >= MTOT) continue;
            const float* Sr = &Sl2[row * 65];
            float v;
            if (cc < 18) {
                int c0 = cc < 9 ? cc : cc - 9;
                float s0 = Sr[c0] + bc[c0];
                float s1 = Sr[c0 + 9] + bc[c0 + 9];
                float mx = fmaxf(s0, s1);
                float e0 = __expf(s0 - mx), e1 = __expf(s1 - mx);
                v = (cc < 9 ? e0 : e1) / (e0 + e1);
            } else {
                v = Sr[cc] + bb[cc - 18];
            }
            int b = m / FHW, hw = m - b * FHW;
            out[(b * 54 + cc) * FHW + hw] = v;
        }
    } else {
        // IoU matrix + labels (idx fused)
        float* g4 = (float*)sm;              // 80 floats
        float* imv = g4 + 80;                // 2
        float* buf = g4 + 84;                // 256*20
        int q = L - CONVB;
        int at = q % 66;
        int b = q / 66;
        int t = tid;
        if (t < NG * 4) g4[t] = gt[b * NG * 4 + t];
        if (t < 2) imv[t] = im[t];
        __syncthreads();
        if (t == 0) {
            float x1, y1, x2, y2;
            anchor_box(19, x1, y1, x2, y2);
            bool inside = (x1 >= 0.f) && (y1 >= 0.f) && (x2 < imv[1]) && (y2 < imv[0]);
            float aa = (x2 - x1) * (y2 - y1);
            float best = -1.f; int bg = 0;
            for (int g2 = 0; g2 < NG; g2++) {
                float gx1 = g4[g2 * 4], gy1 = g4[g2 * 4 + 1], gx2 = g4[g2 * 4 + 2], gy2 = g4[g2 * 4 + 3];
                float l = fmaxf(x1, gx1), r = fminf(x2, gx2);
                float tp = fmaxf(y1, gy1), bo = fminf(y2, gy2);
                float v = 0.f;
                if (l < r && tp < bo) {
                    float inter = (r - l) * (bo - tp);
                    float ag = (gx2 - gx1) * (gy2 - gy1);
                    v = inter / (aa + ag - inter);
                }
                if (!inside) v = 0.f;
                if (v > best) { best = v; bg = g2; }
            }
            idxs = bg;
        }
        int a0 = at * 256;
        int a = a0 + t;
        float mx = 0.f;
        bool inside = false;
        if (a < ANCH) {
            float x1, y1, x2, y2;
            anchor_box(a, x1, y1, x2, y2);
            inside = (x1 >= 0.f) && (y1 >= 0.f) && (x2 < imv[1]) && (y2 < imv[0]);
            float aa = (x2 - x1) * (y2 - y1);
            for (int g2 = 0; g2 < NG; g2++) {
                float gx1 = g4[g2 * 4], gy1 = g4[g2 * 4 + 1], gx2 = g4[g2 * 4 + 2], gy2 = g4[g2 * 4 + 3];
                float l = fmaxf(x1, gx1), r = fminf(x2, gx2);
                float tp = fmaxf(y1, gy1), bo = fminf(y2, gy2);
                float v = 0.f;
                if (l < r && tp < bo) {
                    float inter = (r - l) * (bo - tp);
                    float ag = (gx2 - gx1) * (gy2 - gy1);
                    v = inter / (aa + ag - inter);
                }
                if (!inside) v = 0.f;
                buf[t * NG + g2] = v;
                mx = fmaxf(mx, v);
            }
        }
        __syncthreads();
        int rem = ANCH - a0;
        int cnt2 = (rem < 256 ? rem : 256) * NG;
        float* dst = iou_out + (b * ANCH + a0) * NG;
        for (int i = t; i < cnt2; i += 256) dst[i] = buf[i];
        if (a < ANCH) {
            float lv = (a == idxs) ? 1.f : 0.f;
            if (inside && mx > 0.7f) lv = 0.f;
            lab[b * ANCH + a] = lv;
        }
    }
}

extern "C" void kernel_launch(void* const* d_in, const int* in_sizes, int n_in,
                              void* d_out, int out_size, void* d_ws, size_t ws_size,
                              hipStream_t stream) {
    (void)in_sizes; (void)n_in; (void)out_size; (void)ws_size;
    const float* feats = (const float*)d_in[0];
    const float* w3    = (const float*)d_in[1];
    const float* b3    = (const float*)d_in[2];
    const float* wc    = (const float*)d_in[3];
    const float* bc    = (const float*)d_in[4];
    const float* wb    = (const float*)d_in[5];
    const float* bb    = (const float*)d_in[6];
    const float* gt    = (const float*)d_in[7];
    const float* im    = (const float*)d_in[8];
    float* out = (float*)d_out;
    char* ws = (char*)d_ws;

    // workspace layout (bytes)
    u16* apad = (u16*)(ws);                    // 8*39*52*512 bf16 = 16,613,376 B
    u16* wt   = (u16*)(ws + 16613376);         // 512*4608 bf16    =  4,718,592 B
    u16* whd  = (u16*)(ws + 21331968);         // 64*512 bf16      =     65,536 B
    u16* act  = (u16*)(ws + 21397504);         // 14800*512 bf16   = 15,155,200 B
    int* cnt  = (int*)(ws + 36552704);         // 116 band counters

    float* iou_out = out + 799200;
    float* lab     = out + 3463200;

    k_pre<<<dim3(PRE_TOT + 1), dim3(256), 0, stream>>>(apad, w3, wt, wc, wb, whd, feats, cnt);
    k_conv<<<dim3(CONVB + IOB), dim3(256), 0, stream>>>(apad, wt, b3, bc, bb, whd, act, cnt,
                                                        gt, im, iou_out, lab, out);
}

// Round 7
// 231.759 us; speedup vs baseline: 1.5864x; 1.5864x over previous
//
#include <hip/hip_runtime.h>

typedef unsigned short u16;
typedef unsigned int u32;
typedef float f32x4 __attribute__((ext_vector_type(4)));
typedef short bf16x8 __attribute__((ext_vector_type(8)));

#define NB 8
#define FH 37
#define FW 50
#define FHW 1850
#define MTOT 14800
#define CIN 512
#define KTOT 4608
#define HP 39
#define WP 52
#define ANCH 16650
#define NG 20

// k_pre block ranges
#define ZB 356            // pad-ring zero
#define WTB 512           // w3 repack (LDS transpose, 1 block per n)
#define WHB 128           // head-weight repack
#define TRB 7424          // NHWC transpose
#define SB  925           // zero S: 925*256 uint4 == 3,788,800 B
#define PRE_TOT (ZB + WTB + WHB + TRB + SB)

// k_conv block ranges
#define CONVB 960         // 116 mb x 8 nb (XCD swizzle; 32 dead blocks)
#define IOB 528           // 66 x 8 iou blocks ride along

// ---------- helpers ----------
__device__ __forceinline__ u16 f2bf(float f) {
    u32 u = __float_as_uint(f);
    u += 0x7fffu + ((u >> 16) & 1u);   // round-to-nearest-even
    return (u16)(u >> 16);
}

__device__ __forceinline__ void gl2lds16(const u16* g, u16* l) {
    __builtin_amdgcn_global_load_lds((const __attribute__((address_space(1))) void*)(g),
                                     (__attribute__((address_space(3))) void*)(l),
                                     16, 0, 0);
}

__device__ __forceinline__ void anchor_box(int a, float& x1, float& y1, float& x2, float& y2) {
    int x = a / 333;
    int rem = a - x * 333;
    int y = rem / 9;
    int r2 = rem - y * 9;
    int si = r2 / 3;
    int bi = r2 - si * 3;
    float s = (float)(8 << si);
    float fx = (float)x, fy = (float)y;
    float ax1, ay1, ax2, ay2;
    if (bi == 0)      { float h = s * 0.5f;  ax1 = fx - h; ay1 = fy - h; ax2 = fx + h; ay2 = fy + h; }
    else if (bi == 1) { float q = s * 0.25f; ax1 = fx - s; ay1 = fy - q; ax2 = fx + s; ay2 = fy + q; }
    else              { float q = s * 0.25f; ax1 = fx - q; ay1 = fy - s; ax2 = fx + q; ay2 = fy + s; }
    x1 = ax1 * 16.f; y1 = ay1 * 16.f; x2 = ax2 * 16.f; y2 = ay2 * 16.f;
}

// ---------- fused prep ----------
__global__ __launch_bounds__(256) void k_pre(u16* __restrict__ apad,
                                             const float* __restrict__ w3, u16* __restrict__ wt,
                                             const float* __restrict__ wc, const float* __restrict__ wb,
                                             u16* __restrict__ whd,
                                             const float* __restrict__ feats,
                                             float* __restrict__ S) {
    __shared__ __attribute__((aligned(16))) char smraw[18432];
    int blk = blockIdx.x;
    int t = threadIdx.x;

    if (blk < ZB) {
        // zero only the 1-px pad ring (interior overwritten by transpose)
        uint4* apad4 = (uint4*)apad;
        int i = blk * 256 + t;               // < 91136
        int img = i / 11392;
        int r = i - img * 11392;
        int u4;
        if (r < 3328) u4 = r;                                   // row 0
        else if (r < 6656) u4 = 126464 + (r - 3328);            // row 38
        else {
            int rp = r - 6656;
            int h = 1 + (rp >> 7);
            int c2 = rp & 127;
            int col = (c2 & 64) ? 51 : 0;
            u4 = (h * 52 + col) * 64 + (c2 & 63);
        }
        apad4[img * 129792 + u4] = make_uint4(0u, 0u, 0u, 0u);
    } else if (blk < ZB + WTB) {
        // w3[n] (512,3,3) -> wt[n][tap*512+ci], coalesced via LDS transpose
        float* lt = (float*)smraw;           // 4608 floats
        int n = blk - ZB;
        const float* src = w3 + n * KTOT;
        for (int i = t; i < KTOT; i += 256) lt[i] = src[i];
        __syncthreads();
        u16* dst = wt + n * KTOT;
        for (int o = t; o < KTOT; o += 256) {
            int tap = o >> 9, ci = o & 511;
            dst[o] = f2bf(lt[ci * 9 + tap]);
        }
    } else if (blk < ZB + WTB + WHB) {
        int i = (blk - ZB - WTB) * 256 + t;
        int n = i >> 9;
        int ci = i & 511;
        float v = 0.f;
        if (n < 18) v = wc[n * 512 + ci];
        else if (n < 54) v = wb[(n - 18) * 512 + ci];
        whd[i] = f2bf(v);
    } else if (blk < ZB + WTB + WHB + TRB) {
        // feats (B,512,37,50) f32 -> apad (B,39,52,512) bf16 interior
        float* tile = (float*)smraw;         // 32x33 floats
        int q = blk - ZB - WTB - WHB;
        int xt = q % 58;
        int r2 = q / 58;
        int ct = r2 & 15;
        int img = r2 >> 4;
        int hw0 = xt * 32, c0 = ct * 32;
        int tx = t & 31, ty4 = t >> 5;
        #pragma unroll
        for (int rr = 0; rr < 4; rr++) {
            int ty = ty4 + rr * 8;
            int hw = hw0 + tx;
            if (hw < FHW) tile[ty * 33 + tx] = feats[(img * 512 + c0 + ty) * FHW + hw];
        }
        __syncthreads();
        #pragma unroll
        for (int rr = 0; rr < 4; rr++) {
            int ty = ty4 + rr * 8;
            int hw2 = hw0 + ty;
            if (hw2 < FHW) {
                int h = hw2 / FW, w = hw2 - h * FW;
                apad[(((img * HP) + h + 1) * WP + (w + 1)) * 512 + c0 + tx] = f2bf(tile[tx * 33 + ty]);
            }
        }
    } else {
        // zero S accumulator (ws is re-poisoned 0xAA before every launch)
        int i = (blk - ZB - WTB - WHB - TRB) * 256 + t;   // < 236800
        ((uint4*)S)[i] = make_uint4(0u, 0u, 0u, 0u);
    }
}

// ---------- 3x3 conv implicit GEMM + in-block head partial + IoU tail ----------
// Conv: BM=128 BN=64 BK=64 full-K. XCD decode: all 8 nb of one mb share L%8.
// Key fusion: head-GEMM K == conv N, and relu is per conv channel, so each
// nb block's relu'd 64-channel slice contributes additively to the head
// scores S[m][c]. Partial = relu_tile(128x64) x whd_slice -> atomicAdd to S.
// NO fences anywhere (round-6 lesson: device-scope fences cost 3x).
__global__ __launch_bounds__(256) void k_conv(const u16* __restrict__ apad,
                                              const u16* __restrict__ wt,
                                              const float* __restrict__ b3,
                                              const u16* __restrict__ whd,
                                              float* __restrict__ S,
                                              const float* __restrict__ gt,
                                              const float* __restrict__ im,
                                              float* __restrict__ iou_out,
                                              float* __restrict__ lab) {
    __shared__ __attribute__((aligned(16))) char sm[24576];
    __shared__ int idxs;
    int L = blockIdx.x;
    int tid = threadIdx.x;

    if (L < CONVB) {
        u16* As = (u16*)sm;                 // 128x64 bf16, 16 KB
        u16* Bs = (u16*)(sm + 16384);       // 64x64 bf16, 8 KB
        int mb = (L & 7) + 8 * (L >> 6);
        int nb = (L >> 3) & 7;
        if (mb >= 116) return;
        int wave = tid >> 6, lane = tid & 63;
        int m0 = mb * 128;
        int n0 = nb * 64;
        int wr = wave >> 1, wn = wave & 1;
        int lm = lane & 15, lq = lane >> 4;
        int l7 = lm & 7;

        f32x4 acc[4][2] = {};

        int rloc = tid >> 3;
        int cg = (tid & 7) ^ (rloc & 7);
        int aBase[4], bBase[2];
        for (int i = 0; i < 4; i++) {
            int m = m0 + i * 32 + rloc; if (m > MTOT - 1) m = MTOT - 1;
            int b = m / FHW; int hw = m - b * FHW;
            int h = hw / FW; int w = hw - h * FW;
            aBase[i] = ((b * HP + h) * WP + w) * 512 + cg * 8;
        }
        for (int j = 0; j < 2; j++)
            bBase[j] = (n0 + j * 32 + rloc) * KTOT + cg * 8;

        u16* aL[4]; u16* bL[2];
        for (int i = 0; i < 4; i++) aL[i] = &As[(i * 32 + wave * 8) * 64];
        for (int j = 0; j < 2; j++) bL[j] = &Bs[(j * 32 + wave * 8) * 64];

        for (int kk = 0; kk < KTOT; kk += 64) {
            int tap = kk >> 9;
            int ci0 = kk & 511;
            int dy = tap / 3, dx = tap - dy * 3;
            int aOfs = (dy * WP + dx) * 512 + ci0;
            gl2lds16(apad + aBase[0] + aOfs, aL[0]);
            gl2lds16(apad + aBase[1] + aOfs, aL[1]);
            gl2lds16(apad + aBase[2] + aOfs, aL[2]);
            gl2lds16(apad + aBase[3] + aOfs, aL[3]);
            gl2lds16(wt + bBase[0] + kk, bL[0]);
            gl2lds16(wt + bBase[1] + kk, bL[1]);
            __syncthreads();
            bf16x8 a[2][4], b[2][2];
            #pragma unroll
            for (int ks = 0; ks < 2; ks++) {
                int slotb = ((ks * 4 + lq) ^ l7) * 8;
                #pragma unroll
                for (int i = 0; i < 4; i++)
                    a[ks][i] = *(const bf16x8*)&As[(wr * 64 + i * 16 + lm) * 64 + slotb];
                #pragma unroll
                for (int j = 0; j < 2; j++)
                    b[ks][j] = *(const bf16x8*)&Bs[(wn * 32 + j * 16 + lm) * 64 + slotb];
            }
            #pragma unroll
            for (int ks = 0; ks < 2; ks++)
                #pragma unroll
                for (int i = 0; i < 4; i++)
                    #pragma unroll
                    for (int j = 0; j < 2; j++)
                        acc[i][j] = __builtin_amdgcn_mfma_f32_16x16x32_bf16(a[ks][i], b[ks][j], acc[i][j], 0, 0, 0);
            __syncthreads();
        }

        // epilogue A: bias + relu -> bf16 tile in LDS (XOR-chunk swizzled rows)
        // (loop's final __syncthreads means As is free to overwrite)
        u16* T = As;                        // 128 rows x 64 cols, row stride 64
        for (int j = 0; j < 2; j++) {
            int nl = wn * 32 + j * 16 + lm;          // local channel 0..63
            float bias = b3[n0 + nl];
            int c8 = nl >> 3, w8 = nl & 7;
            for (int i = 0; i < 4; i++) {
                int mrow = wr * 64 + i * 16 + lq * 4;
                for (int r = 0; r < 4; r++) {
                    int ml = mrow + r;
                    float v = acc[i][j][r] + bias;
                    T[ml * 64 + (c8 ^ (ml & 7)) * 8 + w8] = f2bf(v > 0.f ? v : 0.f);
                }
            }
        }
        __syncthreads();

        // epilogue B: head partial GEMM (M=128, N=64 cols incl. pad, K=64 slice)
        f32x4 accP[2][4] = {};
        #pragma unroll
        for (int ks = 0; ks < 2; ks++) {
            bf16x8 a2[2], b2[4];
            int cch = ks * 4 + lq;
            #pragma unroll
            for (int ii = 0; ii < 2; ii++) {
                int ml = (wave * 2 + ii) * 16 + lm;
                a2[ii] = *(const bf16x8*)&T[ml * 64 + (cch ^ (ml & 7)) * 8];
            }
            #pragma unroll
            for (int j = 0; j < 4; j++)
                b2[j] = *(const bf16x8*)&whd[(j * 16 + lm) * 512 + n0 + ks * 32 + lq * 8];
            #pragma unroll
            for (int ii = 0; ii < 2; ii++)
                #pragma unroll
                for (int j = 0; j < 4; j++)
                    accP[ii][j] = __builtin_amdgcn_mfma_f32_16x16x32_bf16(a2[ii], b2[j], accP[ii][j], 0, 0, 0);
        }
        // accumulate into S (fire-and-forget device atomics, no fences)
        #pragma unroll
        for (int ii = 0; ii < 2; ii++) {
            #pragma unroll
            for (int j = 0; j < 4; j++) {
                int c = j * 16 + lm;
                if (c >= 54) continue;
                #pragma unroll
                for (int r = 0; r < 4; r++) {
                    int m = m0 + (wave * 2 + ii) * 16 + lq * 4 + r;
                    if (m < MTOT) atomicAdd(&S[m * 64 + c], accP[ii][j][r]);
                }
            }
        }
    } else {
        // IoU matrix + labels (idx fused)
        float* g4 = (float*)sm;              // 80 floats
        float* imv = g4 + 80;                // 2
        float* buf = g4 + 84;                // 256*20
        int q = L - CONVB;
        int at = q % 66;
        int b = q / 66;
        int t = tid;
        if (t < NG * 4) g4[t] = gt[b * NG * 4 + t];
        if (t < 2) imv[t] = im[t];
        __syncthreads();
        if (t == 0) {
            float x1, y1, x2, y2;
            anchor_box(19, x1, y1, x2, y2);
            bool inside = (x1 >= 0.f) && (y1 >= 0.f) && (x2 < imv[1]) && (y2 < imv[0]);
            float aa = (x2 - x1) * (y2 - y1);
            float best = -1.f; int bg = 0;
            for (int g2 = 0; g2 < NG; g2++) {
                float gx1 = g4[g2 * 4], gy1 = g4[g2 * 4 + 1], gx2 = g4[g2 * 4 + 2], gy2 = g4[g2 * 4 + 3];
                float l = fmaxf(x1, gx1), r = fminf(x2, gx2);
                float tp = fmaxf(y1, gy1), bo = fminf(y2, gy2);
                float v = 0.f;
                if (l < r && tp < bo) {
                    float inter = (r - l) * (bo - tp);
                    float ag = (gx2 - gx1) * (gy2 - gy1);
                    v = inter / (aa + ag - inter);
                }
                if (!inside) v = 0.f;
                if (v > best) { best = v; bg = g2; }
            }
            idxs = bg;
        }
        int a0 = at * 256;
        int a = a0 + t;
        float mx = 0.f;
        bool inside = false;
        if (a < ANCH) {
            float x1, y1, x2, y2;
            anchor_box(a, x1, y1, x2, y2);
            inside = (x1 >= 0.f) && (y1 >= 0.f) && (x2 < imv[1]) && (y2 < imv[0]);
            float aa = (x2 - x1) * (y2 - y1);
            for (int g2 = 0; g2 < NG; g2++) {
                float gx1 = g4[g2 * 4], gy1 = g4[g2 * 4 + 1], gx2 = g4[g2 * 4 + 2], gy2 = g4[g2 * 4 + 3];
                float l = fmaxf(x1, gx1), r = fminf(x2, gx2);
                float tp = fmaxf(y1, gy1), bo = fminf(y2, gy2);
                float v = 0.f;
                if (l < r && tp < bo) {
                    float inter = (r - l) * (bo - tp);
                    float ag = (gx2 - gx1) * (gy2 - gy1);
                    v = inter / (aa + ag - inter);
                }
                if (!inside) v = 0.f;
                buf[t * NG + g2] = v;
                mx = fmaxf(mx, v);
            }
        }
        __syncthreads();
        int rem = ANCH - a0;
        int cnt2 = (rem < 256 ? rem : 256) * NG;
        float* dst = iou_out + (b * ANCH + a0) * NG;
        for (int i = t; i < cnt2; i += 256) dst[i] = buf[i];
        if (a < ANCH) {
            float lv = (a == idxs) ? 1.f : 0.f;
            if (inside && mx > 0.7f) lv = 0.f;
            lab[b * ANCH + a] = lv;
        }
    }
}

// ---------- softmax pairs + bbox bias from S, coalesced write ----------
__global__ __launch_bounds__(256) void k_final(const float* __restrict__ S,
                                               const float* __restrict__ bc,
                                               const float* __restrict__ bb,
                                               float* __restrict__ out) {
    int m = blockIdx.x * 256 + threadIdx.x;
    if (m >= MTOT) return;
    int b = m / FHW;
    int hw = m - b * FHW;
    float* ob = out + b * 54 * FHW + hw;
    const float* s = S + m * 64;
    #pragma unroll
    for (int c = 0; c < 9; c++) {
        float s0 = s[c] + bc[c];
        float s1 = s[c + 9] + bc[c + 9];
        float mxv = fmaxf(s0, s1);
        float e0 = __expf(s0 - mxv), e1 = __expf(s1 - mxv);
        float inv = 1.f / (e0 + e1);
        ob[c * FHW] = e0 * inv;
        ob[(c + 9) * FHW] = e1 * inv;
    }
    #pragma unroll
    for (int j = 0; j < 36; j++)
        ob[(18 + j) * FHW] = s[18 + j] + bb[j];
}

extern "C" void kernel_launch(void* const* d_in, const int* in_sizes, int n_in,
                              void* d_out, int out_size, void* d_ws, size_t ws_size,
                              hipStream_t stream) {
    (void)in_sizes; (void)n_in; (void)out_size; (void)ws_size;
    const float* feats = (const float*)d_in[0];
    const float* w3    = (const float*)d_in[1];
    const float* b3    = (const float*)d_in[2];
    const float* wc    = (const float*)d_in[3];
    const float* bc    = (const float*)d_in[4];
    const float* wb    = (const float*)d_in[5];
    const float* bb    = (const float*)d_in[6];
    const float* gt    = (const float*)d_in[7];
    const float* im    = (const float*)d_in[8];
    float* out = (float*)d_out;
    char* ws = (char*)d_ws;

    // workspace layout (bytes)
    u16* apad = (u16*)(ws);                    // 8*39*52*512 bf16 = 16,613,376 B
    u16* wt   = (u16*)(ws + 16613376);         // 512*4608 bf16    =  4,718,592 B
    u16* whd  = (u16*)(ws + 21331968);         // 64*512 bf16      =     65,536 B
    float* S  = (float*)(ws + 21397504);       // 14800*64 f32     =  3,788,800 B

    float* iou_out = out + 799200;
    float* lab     = out + 3463200;

    k_pre<<<dim3(PRE_TOT), dim3(256), 0, stream>>>(apad, w3, wt, wc, wb, whd, feats, S);
    k_conv<<<dim3(CONVB + IOB), dim3(256), 0, stream>>>(apad, wt, b3, whd, S,
                                                        gt, im, iou_out, lab);
    k_final<<<dim3(58), dim3(256), 0, stream>>>(S, bc, bb, out);
}

// Round 8
// 198.872 us; speedup vs baseline: 1.8487x; 1.1654x over previous
//
#include <hip/hip_runtime.h>

typedef unsigned short u16;
typedef unsigned int u32;
typedef float f32x4 __attribute__((ext_vector_type(4)));
typedef short bf16x8 __attribute__((ext_vector_type(8)));

#define NB 8
#define FH 37
#define FW 50
#define FHW 1850
#define MTOT 14800
#define CIN 512
#define KTOT 4608
#define HP 39
#define WP 52
#define ANCH 16650
#define NG 20

// k_pre block ranges
#define ZB 356            // pad-ring zero
#define WTB 512           // w3 repack (LDS transpose, 1 block per n)
#define WHB 128           // head-weight repack
#define TRB 3712          // NHWC transpose: 58 hw x 8 ctile x 8 img, u32 stores
#define PRE_TOT (ZB + WTB + WHB + TRB)

// k_conv block ranges
#define CONVB 960         // 116 mb x 8 nb (XCD swizzle; 32 dead blocks)
#define IOB 528           // 66 x 8 iou blocks ride along

// ---------- helpers ----------
__device__ __forceinline__ u16 f2bf(float f) {
    u32 u = __float_as_uint(f);
    u += 0x7fffu + ((u >> 16) & 1u);   // round-to-nearest-even
    return (u16)(u >> 16);
}

__device__ __forceinline__ void gl2lds16(const u16* g, u16* l) {
    __builtin_amdgcn_global_load_lds((const __attribute__((address_space(1))) void*)(g),
                                     (__attribute__((address_space(3))) void*)(l),
                                     16, 0, 0);
}

__device__ __forceinline__ void anchor_box(int a, float& x1, float& y1, float& x2, float& y2) {
    int x = a / 333;
    int rem = a - x * 333;
    int y = rem / 9;
    int r2 = rem - y * 9;
    int si = r2 / 3;
    int bi = r2 - si * 3;
    float s = (float)(8 << si);
    float fx = (float)x, fy = (float)y;
    float ax1, ay1, ax2, ay2;
    if (bi == 0)      { float h = s * 0.5f;  ax1 = fx - h; ay1 = fy - h; ax2 = fx + h; ay2 = fy + h; }
    else if (bi == 1) { float q = s * 0.25f; ax1 = fx - s; ay1 = fy - q; ax2 = fx + s; ay2 = fy + q; }
    else              { float q = s * 0.25f; ax1 = fx - q; ay1 = fy - s; ax2 = fx + q; ay2 = fy + s; }
    x1 = ax1 * 16.f; y1 = ay1 * 16.f; x2 = ax2 * 16.f; y2 = ay2 * 16.f;
}

// ---------- fused prep ----------
__global__ __launch_bounds__(256) void k_pre(u16* __restrict__ apad,
                                             const float* __restrict__ w3, u16* __restrict__ wt,
                                             const float* __restrict__ wc, const float* __restrict__ wb,
                                             u16* __restrict__ whd,
                                             const float* __restrict__ feats) {
    __shared__ __attribute__((aligned(16))) char smraw[18432];
    int blk = blockIdx.x;
    int t = threadIdx.x;

    if (blk < ZB) {
        // zero only the 1-px pad ring (interior overwritten by transpose)
        uint4* apad4 = (uint4*)apad;
        int i = blk * 256 + t;               // < 91136
        int img = i / 11392;
        int r = i - img * 11392;
        int u4;
        if (r < 3328) u4 = r;                                   // row 0
        else if (r < 6656) u4 = 126464 + (r - 3328);            // row 38
        else {
            int rp = r - 6656;
            int h = 1 + (rp >> 7);
            int c2 = rp & 127;
            int col = (c2 & 64) ? 51 : 0;
            u4 = (h * 52 + col) * 64 + (c2 & 63);
        }
        apad4[img * 129792 + u4] = make_uint4(0u, 0u, 0u, 0u);
    } else if (blk < ZB + WTB) {
        // w3[n] (512,3,3) -> wt[n][tap*512+ci], coalesced via LDS transpose
        float* lt = (float*)smraw;           // 4608 floats
        int n = blk - ZB;
        const float* src = w3 + n * KTOT;
        for (int i = t; i < KTOT; i += 256) lt[i] = src[i];
        __syncthreads();
        u16* dst = wt + n * KTOT;
        for (int o = t; o < KTOT; o += 256) {
            int tap = o >> 9, ci = o & 511;
            dst[o] = f2bf(lt[ci * 9 + tap]);
        }
    } else if (blk < ZB + WTB + WHB) {
        int i = (blk - ZB - WTB) * 256 + t;
        int n = i >> 9;
        int ci = i & 511;
        float v = 0.f;
        if (n < 18) v = wc[n * 512 + ci];
        else if (n < 54) v = wb[(n - 18) * 512 + ci];
        whd[i] = f2bf(v);
    } else {
        // feats (B,512,37,50) f32 -> apad (B,39,52,512) bf16 interior.
        // Tile: 32 hw x 64 c; stores pack 2 channels/lane (u32, 128-B segments).
        float* tile = (float*)smraw;         // 64 x 33 floats
        int q = blk - ZB - WTB - WHB;
        int xt = q % 58;
        int r2 = q / 58;
        int ct = r2 & 7;                     // 8 c-tiles of 64
        int img = r2 >> 3;
        int hw0 = xt * 32, c0 = ct * 64;
        int lx = t & 31, ly = t >> 5;        // ly 0..7
        #pragma unroll
        for (int rr = 0; rr < 8; rr++) {
            int cl = ly + rr * 8;            // 0..63
            int hw = hw0 + lx;
            if (hw < FHW) tile[cl * 33 + lx] = feats[(img * 512 + c0 + cl) * FHW + hw];
        }
        __syncthreads();
        #pragma unroll
        for (int rr = 0; rr < 4; rr++) {
            int hwl = ly + rr * 8;           // 0..31
            int hw2 = hw0 + hwl;
            if (hw2 < FHW) {
                int h = hw2 / FW, w = hw2 - h * FW;
                float v0 = tile[(2 * lx) * 33 + hwl];
                float v1 = tile[(2 * lx + 1) * 33 + hwl];
                u32 pk = (u32)f2bf(v0) | ((u32)f2bf(v1) << 16);
                u32* dst = (u32*)&apad[(((img * HP) + h + 1) * WP + (w + 1)) * 512 + c0];
                dst[lx] = pk;
            }
        }
    }
}

// ---------- 3x3 conv as implicit GEMM + IoU tail ----------
// BM=128 BN=64 BK=64 full-K, bf16 act epilogue. XCD decode: all 8 nb of one
// mb share L%8 (one XCD) for A-tile L2 reuse. No fences/atomics (R6/R7 lessons).
__global__ __launch_bounds__(256) void k_conv(const u16* __restrict__ apad,
                                              const u16* __restrict__ wt,
                                              const float* __restrict__ b3,
                                              u16* __restrict__ act,
                                              const float* __restrict__ gt,
                                              const float* __restrict__ im,
                                              float* __restrict__ iou_out,
                                              float* __restrict__ lab) {
    __shared__ __attribute__((aligned(16))) char sm[24576];
    __shared__ int idxs;
    int L = blockIdx.x;
    int tid = threadIdx.x;

    if (L < CONVB) {
        u16* As = (u16*)sm;                 // 128x64 bf16, 16 KB
        u16* Bs = (u16*)(sm + 16384);       // 64x64 bf16, 8 KB
        int mb = (L & 7) + 8 * (L >> 6);
        int nb = (L >> 3) & 7;
        if (mb >= 116) return;
        int wave = tid >> 6, lane = tid & 63;
        int m0 = mb * 128;
        int n0 = nb * 64;
        int wr = wave >> 1, wn = wave & 1;
        int lm = lane & 15, lq = lane >> 4;
        int l7 = lm & 7;

        f32x4 acc[4][2] = {};

        int rloc = tid >> 3;
        int cg = (tid & 7) ^ (rloc & 7);
        int aBase[4], bBase[2];
        for (int i = 0; i < 4; i++) {
            int m = m0 + i * 32 + rloc; if (m > MTOT - 1) m = MTOT - 1;
            int b = m / FHW; int hw = m - b * FHW;
            int h = hw / FW; int w = hw - h * FW;
            aBase[i] = ((b * HP + h) * WP + w) * 512 + cg * 8;
        }
        for (int j = 0; j < 2; j++)
            bBase[j] = (n0 + j * 32 + rloc) * KTOT + cg * 8;

        u16* aL[4]; u16* bL[2];
        for (int i = 0; i < 4; i++) aL[i] = &As[(i * 32 + wave * 8) * 64];
        for (int j = 0; j < 2; j++) bL[j] = &Bs[(j * 32 + wave * 8) * 64];

        for (int kk = 0; kk < KTOT; kk += 64) {
            int tap = kk >> 9;
            int ci0 = kk & 511;
            int dy = tap / 3, dx = tap - dy * 3;
            int aOfs = (dy * WP + dx) * 512 + ci0;
            gl2lds16(apad + aBase[0] + aOfs, aL[0]);
            gl2lds16(apad + aBase[1] + aOfs, aL[1]);
            gl2lds16(apad + aBase[2] + aOfs, aL[2]);
            gl2lds16(apad + aBase[3] + aOfs, aL[3]);
            gl2lds16(wt + bBase[0] + kk, bL[0]);
            gl2lds16(wt + bBase[1] + kk, bL[1]);
            __syncthreads();
            bf16x8 a[2][4], b[2][2];
            #pragma unroll
            for (int ks = 0; ks < 2; ks++) {
                int slotb = ((ks * 4 + lq) ^ l7) * 8;
                #pragma unroll
                for (int i = 0; i < 4; i++)
                    a[ks][i] = *(const bf16x8*)&As[(wr * 64 + i * 16 + lm) * 64 + slotb];
                #pragma unroll
                for (int j = 0; j < 2; j++)
                    b[ks][j] = *(const bf16x8*)&Bs[(wn * 32 + j * 16 + lm) * 64 + slotb];
            }
            #pragma unroll
            for (int ks = 0; ks < 2; ks++)
                #pragma unroll
                for (int i = 0; i < 4; i++)
                    #pragma unroll
                    for (int j = 0; j < 2; j++)
                        acc[i][j] = __builtin_amdgcn_mfma_f32_16x16x32_bf16(a[ks][i], b[ks][j], acc[i][j], 0, 0, 0);
            __syncthreads();
        }

        // epilogue: bias + relu + bf16 act
        for (int j = 0; j < 2; j++) {
            int n = n0 + wn * 32 + j * 16 + lm;
            float bias = b3[n];
            for (int i = 0; i < 4; i++) {
                int mb2 = m0 + wr * 64 + i * 16 + lq * 4;
                for (int r = 0; r < 4; r++) {
                    int m = mb2 + r;
                    if (m < MTOT) {
                        float v = acc[i][j][r] + bias;
                        act[m * 512 + n] = f2bf(v > 0.f ? v : 0.f);
                    }
                }
            }
        }
    } else {
        // IoU matrix + labels (idx fused)
        float* g4 = (float*)sm;              // 80 floats
        float* imv = g4 + 80;                // 2
        float* buf = g4 + 84;                // 256*20
        int q = L - CONVB;
        int at = q % 66;
        int b = q / 66;
        int t = tid;
        if (t < NG * 4) g4[t] = gt[b * NG * 4 + t];
        if (t < 2) imv[t] = im[t];
        __syncthreads();
        if (t == 0) {
            float x1, y1, x2, y2;
            anchor_box(19, x1, y1, x2, y2);
            bool inside = (x1 >= 0.f) && (y1 >= 0.f) && (x2 < imv[1]) && (y2 < imv[0]);
            float aa = (x2 - x1) * (y2 - y1);
            float best = -1.f; int bg = 0;
            for (int g2 = 0; g2 < NG; g2++) {
                float gx1 = g4[g2 * 4], gy1 = g4[g2 * 4 + 1], gx2 = g4[g2 * 4 + 2], gy2 = g4[g2 * 4 + 3];
                float l = fmaxf(x1, gx1), r = fminf(x2, gx2);
                float tp = fmaxf(y1, gy1), bo = fminf(y2, gy2);
                float v = 0.f;
                if (l < r && tp < bo) {
                    float inter = (r - l) * (bo - tp);
                    float ag = (gx2 - gx1) * (gy2 - gy1);
                    v = inter / (aa + ag - inter);
                }
                if (!inside) v = 0.f;
                if (v > best) { best = v; bg = g2; }
            }
            idxs = bg;
        }
        int a0 = at * 256;
        int a = a0 + t;
        float mx = 0.f;
        bool inside = false;
        if (a < ANCH) {
            float x1, y1, x2, y2;
            anchor_box(a, x1, y1, x2, y2);
            inside = (x1 >= 0.f) && (y1 >= 0.f) && (x2 < imv[1]) && (y2 < imv[0]);
            float aa = (x2 - x1) * (y2 - y1);
            for (int g2 = 0; g2 < NG; g2++) {
                float gx1 = g4[g2 * 4], gy1 = g4[g2 * 4 + 1], gx2 = g4[g2 * 4 + 2], gy2 = g4[g2 * 4 + 3];
                float l = fmaxf(x1, gx1), r = fminf(x2, gx2);
                float tp = fmaxf(y1, gy1), bo = fminf(y2, gy2);
                float v = 0.f;
                if (l < r && tp < bo) {
                    float inter = (r - l) * (bo - tp);
                    float ag = (gx2 - gx1) * (gy2 - gy1);
                    v = inter / (aa + ag - inter);
                }
                if (!inside) v = 0.f;
                buf[t * NG + g2] = v;
                mx = fmaxf(mx, v);
            }
        }
        __syncthreads();
        int rem = ANCH - a0;
        int cnt2 = (rem < 256 ? rem : 256) * NG;
        float* dst = iou_out + (b * ANCH + a0) * NG;
        for (int i = t; i < cnt2; i += 256) dst[i] = buf[i];
        if (a < ANCH) {
            float lv = (a == idxs) ? 1.f : 0.f;
            if (inside && mx > 0.7f) lv = 0.f;
            lab[b * ANCH + a] = lv;
        }
    }
}

// ---------- fused 1x1 heads + softmax/bias + concat write ----------
// 232 blocks x 4 waves; each wave: 16 rows x 64 cols GEMM -> LDS -> epilogue.
__global__ __launch_bounds__(256) void k_post(const u16* __restrict__ act,
                                              const u16* __restrict__ whd,
                                              const float* __restrict__ bc,
                                              const float* __restrict__ bb,
                                              float* __restrict__ out) {
    __shared__ float Sl[4 * 16 * 65];
    int tid = threadIdx.x;
    int wave = tid >> 6, lane = tid & 63;
    int lm = lane & 15, lq = lane >> 4;
    int m0 = blockIdx.x * 64 + wave * 16;
    int mr = m0 + lm; if (mr > MTOT - 1) mr = MTOT - 1;
    const u16* arow = act + mr * 512;
    f32x4 acc[4] = {};
    for (int kk = 0; kk < 512; kk += 32) {
        bf16x8 a = *(const bf16x8*)&arow[kk + lq * 8];
        #pragma unroll
        for (int j = 0; j < 4; j++) {
            bf16x8 b = *(const bf16x8*)&whd[(j * 16 + lm) * 512 + kk + lq * 8];
            acc[j] = __builtin_amdgcn_mfma_f32_16x16x32_bf16(a, b, acc[j], 0, 0, 0);
        }
    }
    float* S = &Sl[wave * 1040];
    #pragma unroll
    for (int r = 0; r < 4; r++)
        #pragma unroll
        for (int j = 0; j < 4; j++)
            S[(lq * 4 + r) * 65 + j * 16 + lm] = acc[j][r];
    __syncthreads();
    int r16 = lane & 15, cg = lane >> 4;
    int m = m0 + r16;
    if (m < MTOT) {
        int b = m / FHW, hw = m - b * FHW;
        const float* Sr = &S[r16 * 65];
        #pragma unroll
        for (int k = 0; k < 14; k++) {
            int c = cg + 4 * k;
            if (c >= 54) break;
            float v;
            if (c < 18) {
                int c0 = c < 9 ? c : c - 9;
                float s0 = Sr[c0] + bc[c0];
                float s1 = Sr[c0 + 9] + bc[c0 + 9];
                float mx = fmaxf(s0, s1);
                float e0 = __expf(s0 - mx), e1 = __expf(s1 - mx);
                v = (c < 9 ? e0 : e1) / (e0 + e1);
            } else {
                v = Sr[c] + bb[c - 18];
            }
            out[(b * 54 + c) * FHW + hw] = v;
        }
    }
}

extern "C" void kernel_launch(void* const* d_in, const int* in_sizes, int n_in,
                              void* d_out, int out_size, void* d_ws, size_t ws_size,
                              hipStream_t stream) {
    (void)in_sizes; (void)n_in; (void)out_size; (void)ws_size;
    const float* feats = (const float*)d_in[0];
    const float* w3    = (const float*)d_in[1];
    const float* b3    = (const float*)d_in[2];
    const float* wc    = (const float*)d_in[3];
    const float* bc    = (const float*)d_in[4];
    const float* wb    = (const float*)d_in[5];
    const float* bb    = (const float*)d_in[6];
    const float* gt    = (const float*)d_in[7];
    const float* im    = (const float*)d_in[8];
    float* out = (float*)d_out;
    char* ws = (char*)d_ws;

    // workspace layout (bytes)
    u16* apad = (u16*)(ws);                    // 8*39*52*512 bf16 = 16,613,376 B
    u16* wt   = (u16*)(ws + 16613376);         // 512*4608 bf16    =  4,718,592 B
    u16* whd  = (u16*)(ws + 21331968);         // 64*512 bf16      =     65,536 B
    u16* act  = (u16*)(ws + 21397504);         // 14800*512 bf16   = 15,155,200 B

    float* iou_out = out + 799200;
    float* lab     = out + 3463200;

    k_pre<<<dim3(PRE_TOT), dim3(256), 0, stream>>>(apad, w3, wt, wc, wb, whd, feats);
    k_conv<<<dim3(CONVB + IOB), dim3(256), 0, stream>>>(apad, wt, b3, act, gt, im, iou_out, lab);
    k_post<<<dim3(232), dim3(256), 0, stream>>>(act, whd, bc, bb, out);
}